// Round 1
// baseline (354.381 us; speedup 1.0000x reference)
//
#include <hip/hip_runtime.h>

// PointNetSaModule fused — f32 in/out, f16 MFMA compute.
// R7: LDS-pipe was the bottleneck (~74% busy: 64 ds_write_u16 + 32 ds_read_b128
// + 32 swizzles per wave-iter; 5.08M bank-conflict cycles from the 4-way-conflict
// u16 scatter). Eliminated ALL activation LDS traffic:
//   - layers 0/1 computed operand-SWAPPED: D = W^T * X^T (mfma(w,x)) so output
//     keeps lane=neighbor; A/B frag index maps are identical on gfx950, so the
//     same folded weights + same gather loads work unchanged.
//   - inter-layer transpose (quad-axis <-> reg-axis) done in-register with
//     v_permlane32_swap + v_permlane16_swap (VALU, not DS): 8 packs + 8 swaps
//     per point per boundary replace 16 ds_write_u16 + 2 ds_read_b128.
//   - layer 2 consumes butterflied frags as normal-orientation A; K-maxpool
//     reduce via permlane swaps (off the DS pipe).
// b0f moved to LDS (frees 48 VGPRs); t1/t2 hoisted to regs via retired s1sh/
// s2sh. LDS 47.6KB -> 39.75KB => 4 blocks/CU, launch_bounds(256,4), grid 1024.

#define NGRP_    8192         // groups of 8 points (B*h*w/8)
#define OUTHALF_ 8388608      // elements: second output copy offset
#define WS_      72           // padded f16 stride of W1'/W2' rows (need 64)
#define W0S_     96           // f16 stride of W0'' rows (64 pts + 3 xyz + bias + pad)
#define EPS_     1e-5f
#define GRID_    1024         // 4 blocks/CU x 256 CUs

typedef _Float16 h8    __attribute__((ext_vector_type(8)));
typedef float    f32x4 __attribute__((ext_vector_type(4)));
typedef unsigned u32x4 __attribute__((ext_vector_type(4)));

__global__ __launch_bounds__(256) void cvt_pts_kernel(
    const float* __restrict__ src, _Float16* __restrict__ dst)
{
    const size_t i = ((size_t)blockIdx.x * 256 + threadIdx.x) * 8;
    f32x4 a = *(const f32x4*)(src + i);
    f32x4 b = *(const f32x4*)(src + i + 4);
    h8 o;
#pragma unroll
    for (int j = 0; j < 4; ++j) { o[j] = (_Float16)a[j]; o[4 + j] = (_Float16)b[j]; }
    *(h8*)(dst + i) = o;
}

// relu + cvt + pack two f32 into one u32 of 2 f16 (RTE casts, same as before)
#define PK(lo, hi) ({                                                          \
    const _Float16 _l = (_Float16)fmaxf((lo), 0.f);                            \
    const _Float16 _h = (_Float16)fmaxf((hi), 0.f);                            \
    (unsigned)__builtin_bit_cast(unsigned short, _l) |                         \
    ((unsigned)__builtin_bit_cast(unsigned short, _h) << 16); })

// v_permlane32_swap: vdst[32..63] <-> src[0..31]
// v_permlane16_swap: vdst rows 1,3 (lanes 16-31,48-63) <-> src rows 0,2
#define SW32(x, y) asm("v_permlane32_swap_b32 %0, %1" : "+v"(x), "+v"(y))
#define SW16(x, y) asm("v_permlane16_swap_b32 %0, %1" : "+v"(x), "+v"(y))

// Input: acc[nt][r] = X[neighbor=l15][ch = 16*nt + 4*quad + r]  (D-layout)
// Output: x0/x1 = B/A-frag of X for k-chunks 0..31 / 32..63:
//         lane(q,l15) reg j holds X[l15][q*8+j] (+32 for x1)
#define BUTTERFLY(acc, x0, x1) do {                                            \
    unsigned _a0 = PK(acc[0][0], acc[0][1]);                                   \
    unsigned _a1 = PK(acc[1][0], acc[1][1]);                                   \
    unsigned _a2 = PK(acc[2][0], acc[2][1]);                                   \
    unsigned _a3 = PK(acc[3][0], acc[3][1]);                                   \
    unsigned _b0 = PK(acc[0][2], acc[0][3]);                                   \
    unsigned _b1 = PK(acc[1][2], acc[1][3]);                                   \
    unsigned _b2 = PK(acc[2][2], acc[2][3]);                                   \
    unsigned _b3 = PK(acc[3][2], acc[3][3]);                                   \
    SW32(_a0, _a1); SW16(_a0, _a1);   /* -> chunk0 pair i0, i2 */              \
    SW32(_a2, _a3); SW16(_a2, _a3);   /* -> chunk1 pair i0, i2 */              \
    SW32(_b0, _b1); SW16(_b0, _b1);   /* -> chunk0 pair i1, i3 */              \
    SW32(_b2, _b3); SW16(_b2, _b3);   /* -> chunk1 pair i1, i3 */              \
    u32x4 _c0 = {_a0, _b0, _a1, _b1};                                          \
    u32x4 _c1 = {_a2, _b2, _a3, _b3};                                          \
    x0 = __builtin_bit_cast(h8, _c0);                                          \
    x1 = __builtin_bit_cast(h8, _c1);                                          \
} while (0)

// xor-16 / xor-32 max-reduce via permlane swaps (VALU, keeps DS pipe free)
#define XMAX16(v) do { float _t = (v);                                         \
    asm("v_permlane16_swap_b32 %0, %1" : "+v"(v), "+v"(_t));                   \
    (v) = fmaxf((v), _t); } while (0)
#define XMAX32(v) do { float _t = (v);                                         \
    asm("v_permlane32_swap_b32 %0, %1" : "+v"(v), "+v"(_t));                   \
    (v) = fmaxf((v), _t); } while (0)

template<bool PRE>   // PRE: pts pre-converted to f16 in workspace
__global__ __launch_bounds__(256, 4) void pnsa_main(
    const float* __restrict__ xyz,    // (B,HW,3) f32
    const void*  __restrict__ ptsv,   // f16 ws if PRE, else f32 (B,HW,64)
    const float* __restrict__ xyzs,   // (B,NPT,3) f32
    const int*   __restrict__ nidx,   // (B,NPT*16)
    const float* __restrict__ vmask,  // (B,NPT,16) f32
    const float* __restrict__ w0, const float* __restrict__ b0,
    const float* __restrict__ g0, const float* __restrict__ be0,
    const float* __restrict__ m0, const float* __restrict__ v0,
    const float* __restrict__ w1, const float* __restrict__ b1,
    const float* __restrict__ g1, const float* __restrict__ be1,
    const float* __restrict__ m1, const float* __restrict__ v1,
    const float* __restrict__ w2, const float* __restrict__ b2,
    const float* __restrict__ g2, const float* __restrict__ be2,
    const float* __restrict__ m2, const float* __restrict__ v2,
    float*       __restrict__ out)
{
    __shared__ __align__(16) _Float16 ldsW0[64 * W0S_];   // W0''[n][k]  12288B
    __shared__ __align__(16) _Float16 ldsW1[64 * WS_];    // W1'[n][k]    9216B
    __shared__ __align__(16) _Float16 ldsW2[128 * WS_];   // W2'[n][k]   18432B
    __shared__ __align__(16) float    s1sh[64];           // s1, then t1   256B
    __shared__ __align__(16) float    s2sh[128];          // s2, then t2   512B

    const int tid  = threadIdx.x;
    const int wave = tid >> 6;
    const int lane = tid & 63;
    const int l15  = lane & 15;
    const int quad = lane >> 4;

    // ---- BN scales ----
    if (tid < 64)  s1sh[tid] = g1[tid] * rsqrtf(v1[tid] + EPS_);
    if (tid < 128) s2sh[tid] = g2[tid] * rsqrtf(v2[tid] + EPS_);
    __syncthreads();

    // ---- fold W1'/W2' into LDS ----
    for (int idx = tid; idx < 64 * 64; idx += 256) {     // w1[k][n] -> W1'[n][k]
        const int k = idx >> 6, n = idx & 63;
        ldsW1[n * WS_ + k] = (_Float16)(w1[idx] * s1sh[n]);
    }
    for (int idx = tid; idx < 64 * 128; idx += 256) {    // w2[k][n] -> W2'[n][k]
        const int k = idx >> 7, n = idx & 127;
        ldsW2[n * WS_ + k] = (_Float16)(w2[idx] * s2sh[n]);
    }
    // ---- fold W0'' (BN + bias channel 67) into LDS ----
    // k-order: [points 0..63, xyz_diff 64..66, BIAS 67 (=1.0 in X), pad..95]
    for (int idx = tid; idx < 64 * W0S_; idx += 256) {
        const int n = idx / W0S_, k = idx - n * W0S_;
        const float s = g0[n] * rsqrtf(v0[n] + EPS_);
        float wv = 0.f;
        if (k < 64)       wv = w0[(3 + k) * 64 + n] * s;
        else if (k < 67)  wv = w0[(k - 64) * 64 + n] * s;
        else if (k == 67) wv = (b0[n] - m0[n]) * s + be0[n];
        ldsW0[n * W0S_ + k] = (_Float16)wv;
    }
    __syncthreads();

    // ---- reuse s1sh/s2sh as shifted biases t1/t2 ----
    if (tid < 64)  s1sh[tid] = (b1[tid] - m1[tid]) * s1sh[tid] + be1[tid];
    if (tid < 128) s2sh[tid] = (b2[tid] - m2[tid]) * s2sh[tid] + be2[tid];
    __syncthreads();

    // t1 per lane: out-ch lives in REGS for swapped layer 1: ch = 16nt+4q+r
    f32x4 t1v[4];
#pragma unroll
    for (int nt = 0; nt < 4; ++nt)
#pragma unroll
        for (int r = 0; r < 4; ++r)
            t1v[nt][r] = s1sh[nt * 16 + quad * 4 + r];
    // t2 per lane: layer 2 is normal orientation: ch = 16nt+l15
    float t2v[8];
#pragma unroll
    for (int nt = 0; nt < 8; ++nt) t2v[nt] = s2sh[nt * 16 + l15];

    // ---- main loop: 8 points per block iteration (2 per wave) ----
    const int g0i = blockIdx.x;
    const int pA0 = (g0i << 3) + (wave << 1);
    int nbA = nidx[(pA0 << 4) + l15];
    int nbB = nidx[((pA0 + 1) << 4) + l15];

    for (int grp = g0i; grp < NGRP_; grp += GRID_) {
        const int pA = (grp << 3) + (wave << 1);
        const int pB = pA + 1;
        const int gn = (grp + GRID_ < NGRP_) ? grp + GRID_ : grp;
        const int pAn = (gn << 3) + (wave << 1);

        // gather loads for both points (issue early)
        const size_t rowA = (size_t)(((pA >> 14) << 16) + nbA);
        const size_t rowB = (size_t)(((pB >> 14) << 16) + nbB);
        h8 qA0, qA1, qB0, qB1;
        if constexpr (PRE) {
            const _Float16* pwA = (const _Float16*)ptsv + (rowA << 6);
            const _Float16* pwB = (const _Float16*)ptsv + (rowB << 6);
            qA0 = *(const h8*)(pwA + quad * 8);
            qA1 = *(const h8*)(pwA + 32 + quad * 8);
            qB0 = *(const h8*)(pwB + quad * 8);
            qB1 = *(const h8*)(pwB + 32 + quad * 8);
        } else {
            const float* pwA = (const float*)ptsv + (rowA << 6);
            const float* pwB = (const float*)ptsv + (rowB << 6);
            f32x4 r0, r1, r2, r3;
            r0 = *(const f32x4*)(pwA + quad * 8);      r1 = *(const f32x4*)(pwA + quad * 8 + 4);
            r2 = *(const f32x4*)(pwA + 32 + quad * 8); r3 = *(const f32x4*)(pwA + 32 + quad * 8 + 4);
#pragma unroll
            for (int j = 0; j < 4; ++j) { qA0[j]=(_Float16)r0[j]; qA0[4+j]=(_Float16)r1[j];
                                          qA1[j]=(_Float16)r2[j]; qA1[4+j]=(_Float16)r3[j]; }
            r0 = *(const f32x4*)(pwB + quad * 8);      r1 = *(const f32x4*)(pwB + quad * 8 + 4);
            r2 = *(const f32x4*)(pwB + 32 + quad * 8); r3 = *(const f32x4*)(pwB + 32 + quad * 8 + 4);
#pragma unroll
            for (int j = 0; j < 4; ++j) { qB0[j]=(_Float16)r0[j]; qB0[4+j]=(_Float16)r1[j];
                                          qB1[j]=(_Float16)r2[j]; qB1[4+j]=(_Float16)r3[j]; }
        }
        const float mkA = vmask[(pA << 4) + l15];
        const float mkB = vmask[(pB << 4) + l15];
        const float* xgA = xyz + rowA * 3;
        const float* xgB = xyz + rowB * 3;
        const float xgA0 = xgA[0], xgA1 = xgA[1], xgA2 = xgA[2];
        const float xgB0 = xgB[0], xgB1 = xgB[1], xgB2 = xgB[2];
        const float* xsA = xyzs + (size_t)pA * 3;
        const float* xsB = xyzs + (size_t)pB * 3;
        const float xsA0 = xsA[0], xsA1 = xsA[1], xsA2 = xsA[2];
        const float xsB0 = xsB[0], xsB1 = xsB[1], xsB2 = xsB[2];

        // prefetch next iteration's neighbor indices
        const int nbAn = nidx[(pAn << 4) + l15];
        const int nbBn = nidx[((pAn + 1) << 4) + l15];

        if (mkA == 0.0f) { qA0 = (h8)(_Float16)0.f; qA1 = (h8)(_Float16)0.f; }
        if (mkB == 0.0f) { qB0 = (h8)(_Float16)0.f; qB1 = (h8)(_Float16)0.f; }
        h8 aA2 = (h8)(_Float16)0.f, aB2 = (h8)(_Float16)0.f;
        if (quad == 0) {
            aA2[0] = (_Float16)(xgA0 * mkA - xsA0);
            aA2[1] = (_Float16)(xgA1 * mkA - xsA1);
            aA2[2] = (_Float16)(xgA2 * mkA - xsA2);
            aA2[3] = (_Float16)1.0f;               // bias channel
            aB2[0] = (_Float16)(xgB0 * mkB - xsB0);
            aB2[1] = (_Float16)(xgB1 * mkB - xsB1);
            aB2[2] = (_Float16)(xgB2 * mkB - xsB2);
            aB2[3] = (_Float16)1.0f;
        }

        // ---- layer 0 SWAPPED: D = W0^T X^T -> lane=neighbor, chs in regs ----
        f32x4 accA[4], accB[4];
#pragma unroll
        for (int nt = 0; nt < 4; ++nt) {
            const _Float16* wr = ldsW0 + (nt * 16 + l15) * W0S_ + quad * 8;
            const h8 w00 = *(const h8*)(wr);
            const h8 w01 = *(const h8*)(wr + 32);
            const h8 w02 = *(const h8*)(wr + 64);
            f32x4 aA = {0.f,0.f,0.f,0.f}, aB = {0.f,0.f,0.f,0.f};
            aA = __builtin_amdgcn_mfma_f32_16x16x32_f16(w00, qA0, aA, 0, 0, 0);
            aA = __builtin_amdgcn_mfma_f32_16x16x32_f16(w01, qA1, aA, 0, 0, 0);
            aA = __builtin_amdgcn_mfma_f32_16x16x32_f16(w02, aA2, aA, 0, 0, 0);
            aB = __builtin_amdgcn_mfma_f32_16x16x32_f16(w00, qB0, aB, 0, 0, 0);
            aB = __builtin_amdgcn_mfma_f32_16x16x32_f16(w01, qB1, aB, 0, 0, 0);
            aB = __builtin_amdgcn_mfma_f32_16x16x32_f16(w02, aB2, aB, 0, 0, 0);
            accA[nt] = aA; accB[nt] = aB;
        }
        h8 xA0, xA1, xB0, xB1;
        BUTTERFLY(accA, xA0, xA1);
        BUTTERFLY(accB, xB0, xB1);

        // ---- layer 1 SWAPPED: bias via acc init (t1v), W1 frags from LDS ----
#pragma unroll
        for (int nt = 0; nt < 4; ++nt) {
            const _Float16* wrow = ldsW1 + (nt * 16 + l15) * WS_ + quad * 8;
            const h8 wa = *(const h8*)(wrow);
            const h8 wb = *(const h8*)(wrow + 32);
            f32x4 aA = t1v[nt], aB = t1v[nt];
            aA = __builtin_amdgcn_mfma_f32_16x16x32_f16(wa, xA0, aA, 0, 0, 0);
            aA = __builtin_amdgcn_mfma_f32_16x16x32_f16(wb, xA1, aA, 0, 0, 0);
            aB = __builtin_amdgcn_mfma_f32_16x16x32_f16(wa, xB0, aB, 0, 0, 0);
            aB = __builtin_amdgcn_mfma_f32_16x16x32_f16(wb, xB1, aB, 0, 0, 0);
            accA[nt] = aA; accB[nt] = aB;
        }
        h8 yA0, yA1, yB0, yB1;
        BUTTERFLY(accA, yA0, yA1);
        BUTTERFLY(accB, yB0, yB1);

        // ---- layer 2 NORMAL: D = X W2' -> lane=out-ch, neighbors in regs ----
        float* obA = out + ((size_t)pA << 7);
        float* obB = out + ((size_t)pB << 7);
#pragma unroll
        for (int nt = 0; nt < 8; ++nt) {
            const _Float16* wrow = ldsW2 + (nt * 16 + l15) * WS_ + quad * 8;
            const h8 wa = *(const h8*)(wrow);
            const h8 wb = *(const h8*)(wrow + 32);
            f32x4 aA = {t2v[nt], t2v[nt], t2v[nt], t2v[nt]};
            f32x4 aB = aA;
            aA = __builtin_amdgcn_mfma_f32_16x16x32_f16(yA0, wa, aA, 0, 0, 0);
            aA = __builtin_amdgcn_mfma_f32_16x16x32_f16(yA1, wb, aA, 0, 0, 0);
            aB = __builtin_amdgcn_mfma_f32_16x16x32_f16(yB0, wa, aB, 0, 0, 0);
            aB = __builtin_amdgcn_mfma_f32_16x16x32_f16(yB1, wb, aB, 0, 0, 0);
            float vA = fmaxf(fmaxf(aA[0], aA[1]), fmaxf(aA[2], aA[3]));
            float vB = fmaxf(fmaxf(aB[0], aB[1]), fmaxf(aB[2], aB[3]));
            vA = fmaxf(vA, 0.f);  vB = fmaxf(vB, 0.f);    // relu(max)=max(relu)
            XMAX16(vA); XMAX32(vA);
            XMAX16(vB); XMAX32(vB);
            if (quad == 0) {
                obA[nt * 16 + l15]            = vA;
                obA[OUTHALF_ + nt * 16 + l15] = vA;
                obB[nt * 16 + l15]            = vB;
                obB[OUTHALF_ + nt * 16 + l15] = vB;
            }
        }

        nbA = nbAn; nbB = nbBn;
    }
}

extern "C" void kernel_launch(void* const* d_in, const int* in_sizes, int n_in,
                              void* d_out, int out_size, void* d_ws, size_t ws_size,
                              hipStream_t stream) {
    const float* xyz   = (const float*)d_in[0];
    const float* pts   = (const float*)d_in[1];
    const float* xyzs  = (const float*)d_in[2];
    const int*   nidx  = (const int*)d_in[3];
    const float* vmask = (const float*)d_in[4];
    const float *w0 = (const float*)d_in[5],  *b0 = (const float*)d_in[6],
                *g0 = (const float*)d_in[7],  *be0 = (const float*)d_in[8],
                *m0 = (const float*)d_in[9],  *v0 = (const float*)d_in[10];
    const float *w1 = (const float*)d_in[11], *b1 = (const float*)d_in[12],
                *g1 = (const float*)d_in[13], *be1 = (const float*)d_in[14],
                *m1 = (const float*)d_in[15], *v1 = (const float*)d_in[16];
    const float *w2 = (const float*)d_in[17], *b2 = (const float*)d_in[18],
                *g2 = (const float*)d_in[19], *be2 = (const float*)d_in[20],
                *m2 = (const float*)d_in[21], *v2 = (const float*)d_in[22];
    float* outp = (float*)d_out;

    const size_t PTS_ELEMS = 16777216ull;           // 4*65536*64
    if (ws_size >= PTS_ELEMS * sizeof(_Float16)) {
        _Float16* ptsh = (_Float16*)d_ws;
        cvt_pts_kernel<<<dim3(8192), dim3(256), 0, stream>>>(pts, ptsh);
        pnsa_main<true><<<dim3(GRID_), dim3(256), 0, stream>>>(
            xyz, (const void*)ptsh, xyzs, nidx, vmask,
            w0, b0, g0, be0, m0, v0,
            w1, b1, g1, be1, m1, v1,
            w2, b2, g2, be2, m2, v2, outp);
    } else {
        pnsa_main<false><<<dim3(GRID_), dim3(256), 0, stream>>>(
            xyz, (const void*)pts, xyzs, nidx, vmask,
            w0, b0, g0, be0, m0, v0,
            w1, b1, g1, be1, m1, v1,
            w2, b2, g2, be2, m2, v2, outp);
    }
}

// Round 4
// 226.185 us; speedup vs baseline: 1.5668x; 1.5668x over previous
//
#include <hip/hip_runtime.h>

// PointNetSaModule fused — f32 in/out, f16 MFMA compute.
// R10: swapped layers 0/1 (R7-validated math) + LDS u32-pair transpose.
// R8/R9 post-mortem: permlane butterfly fails under spill-free regalloc with
// BOTH asm and builtins (absmax 2.2/2.7) but passed under R7's spill-padded
// schedule -> un-modeled permlane hazard or regalloc bug. Permlane is BANNED.
// Transport goes through LDS instead, exploiting the swapped D-layout:
//   lane(q,l) holds channels 16nt+4q+{0..3} of neighbor l -> PK to 2 adjacent
//   u32 -> ONE ds_write_b64 per nt per point into X'[nb][ch/2] (stride 36 u32).
//   16 b64 writes/wave-iter vs R6's 64 conflicted ds_write_u16.
//   Banks: writes 4l+2q+8nt -> 4 words/bank (min, conflict-free);
//   b128 reads at l*36+4q u32 -> 16B-aligned, 8 words/bank (min, free).
// Layer 2 normal orientation + R6-proven shfl_xor K-maxpool reduce.
// b0f in regs (A/B frag maps identical -> same values serve swapped A-operand).
// t1 via ds_read_b128 from t1sh per nt; t2 scalar from t2sh (no runtime-indexed
// reg arrays under partial unroll). Config (256,3)/768, LDS 47616B = R6 exact.

#define NGRP_    8192         // groups of 8 points (B*h*w/8)
#define OUTHALF_ 8388608      // elements: second output copy offset
#define WS_      72           // padded f16 stride of W1'/W2' rows (need 64)
#define XS2_     36           // u32 stride of X' rows (need 32; 144B, 16B-mult)
#define EPS_     1e-5f
#define GRID_    768          // 3 blocks/CU x 256 CUs

typedef _Float16 h8    __attribute__((ext_vector_type(8)));
typedef float    f32x4 __attribute__((ext_vector_type(4)));
typedef unsigned u32x2 __attribute__((ext_vector_type(2)));

__global__ __launch_bounds__(256) void cvt_pts_kernel(
    const float* __restrict__ src, _Float16* __restrict__ dst)
{
    const size_t i = ((size_t)blockIdx.x * 256 + threadIdx.x) * 8;
    f32x4 a = *(const f32x4*)(src + i);
    f32x4 b = *(const f32x4*)(src + i + 4);
    h8 o;
#pragma unroll
    for (int j = 0; j < 4; ++j) { o[j] = (_Float16)a[j]; o[4 + j] = (_Float16)b[j]; }
    *(h8*)(dst + i) = o;
}

// relu + cvt + pack two f32 into one u32 of 2 f16 (RTE casts, R6 numerics)
#define PK(lo, hi) ({                                                          \
    const _Float16 _l = (_Float16)fmaxf((lo), 0.f);                            \
    const _Float16 _h = (_Float16)fmaxf((hi), 0.f);                            \
    (unsigned)__builtin_bit_cast(unsigned short, _l) |                         \
    ((unsigned)__builtin_bit_cast(unsigned short, _h) << 16); })

template<bool PRE>   // PRE: pts pre-converted to f16 in workspace
__global__ __launch_bounds__(256, 3) void pnsa_main(
    const float* __restrict__ xyz,    // (B,HW,3) f32
    const void*  __restrict__ ptsv,   // f16 ws if PRE, else f32 (B,HW,64)
    const float* __restrict__ xyzs,   // (B,NPT,3) f32
    const int*   __restrict__ nidx,   // (B,NPT*16)
    const float* __restrict__ vmask,  // (B,NPT,16) f32
    const float* __restrict__ w0, const float* __restrict__ b0,
    const float* __restrict__ g0, const float* __restrict__ be0,
    const float* __restrict__ m0, const float* __restrict__ v0,
    const float* __restrict__ w1, const float* __restrict__ b1,
    const float* __restrict__ g1, const float* __restrict__ be1,
    const float* __restrict__ m1, const float* __restrict__ v1,
    const float* __restrict__ w2, const float* __restrict__ b2,
    const float* __restrict__ g2, const float* __restrict__ be2,
    const float* __restrict__ m2, const float* __restrict__ v2,
    float*       __restrict__ out)
{
    __shared__ __align__(16) _Float16 ldsW1[64 * WS_];        // W1'[n][k]  9216B
    __shared__ __align__(16) _Float16 ldsW2[128 * WS_];       // W2'[n][k] 18432B
    __shared__ __align__(16) float    s1sh[64], t1sh[64];     //             512B
    __shared__ __align__(16) float    s2sh[128], t2sh[128];   //            1024B
    __shared__ __align__(16) unsigned ldsX[4][2][16 * XS2_];  // X' u32   18432B

    const int tid  = threadIdx.x;
    const int wave = tid >> 6;
    const int lane = tid & 63;
    const int l15  = lane & 15;
    const int quad = lane >> 4;

    unsigned* XA = &ldsX[wave][0][0];
    unsigned* XB = &ldsX[wave][1][0];

    // ---- stage BN scales + shifted biases, then W1'/W2' folded into LDS ----
    if (tid < 64) {
        const float s = g1[tid] * rsqrtf(v1[tid] + EPS_);
        s1sh[tid] = s;
        t1sh[tid] = (b1[tid] - m1[tid]) * s + be1[tid];
    }
    if (tid < 128) {
        const float s = g2[tid] * rsqrtf(v2[tid] + EPS_);
        s2sh[tid] = s;
        t2sh[tid] = (b2[tid] - m2[tid]) * s + be2[tid];
    }
    __syncthreads();
    for (int idx = tid; idx < 64 * 64; idx += 256) {     // w1[k][n] -> W1'[n][k]
        const int k = idx >> 6, n = idx & 63;
        ldsW1[n * WS_ + k] = (_Float16)(w1[idx] * s1sh[n]);
    }
    for (int idx = tid; idx < 64 * 128; idx += 256) {    // w2[k][n] -> W2'[n][k]
        const int k = idx >> 7, n = idx & 127;
        ldsW2[n * WS_ + k] = (_Float16)(w2[idx] * s2sh[n]);
    }
    __syncthreads();

    // ---- W0 BN-folded into register frags; bias via pad channel 67 ----
    // Feature k-order: [points 0..63, xyz_diff 64..66, BIAS 67 (=1.0), pad..95]
    // Frag map (A and B identical on gfx950): lane holds [ch=nt*16+l15][k=kk*32+quad*8+j]
    h8 b0f[4][3];
#pragma unroll
    for (int nt = 0; nt < 4; ++nt) {
        const int ch = nt * 16 + l15;
        const float s = g0[ch] * rsqrtf(v0[ch] + EPS_);
        const float t0 = (b0[ch] - m0[ch]) * s + be0[ch];
#pragma unroll
        for (int kk = 0; kk < 3; ++kk) {
            h8 f;
#pragma unroll
            for (int j = 0; j < 8; ++j) {
                const int k = kk * 32 + quad * 8 + j;
                float wv = 0.f;
                if (k < 64)       wv = w0[(3 + k) * 64 + ch] * s;
                else if (k < 67)  wv = w0[(k - 64) * 64 + ch] * s;
                else if (k == 67) wv = t0;                 // bias via 1.0 channel
                f[j] = (_Float16)wv;
            }
            b0f[nt][kk] = f;
        }
    }

    // ---- main loop: 8 points per block iteration (2 per wave) ----
    const int g0i = blockIdx.x;
    const int pA0 = (g0i << 3) + (wave << 1);
    int nbA = nidx[(pA0 << 4) + l15];
    int nbB = nidx[((pA0 + 1) << 4) + l15];

    for (int grp = g0i; grp < NGRP_; grp += GRID_) {
        const int pA = (grp << 3) + (wave << 1);
        const int pB = pA + 1;
        const int gn = (grp + GRID_ < NGRP_) ? grp + GRID_ : grp;
        const int pAn = (gn << 3) + (wave << 1);

        // gather loads for both points (issue early)
        const size_t rowA = (size_t)(((pA >> 14) << 16) + nbA);
        const size_t rowB = (size_t)(((pB >> 14) << 16) + nbB);
        h8 qA0, qA1, qB0, qB1;
        if constexpr (PRE) {
            const _Float16* pwA = (const _Float16*)ptsv + (rowA << 6);
            const _Float16* pwB = (const _Float16*)ptsv + (rowB << 6);
            qA0 = *(const h8*)(pwA + quad * 8);
            qA1 = *(const h8*)(pwA + 32 + quad * 8);
            qB0 = *(const h8*)(pwB + quad * 8);
            qB1 = *(const h8*)(pwB + 32 + quad * 8);
        } else {
            const float* pwA = (const float*)ptsv + (rowA << 6);
            const float* pwB = (const float*)ptsv + (rowB << 6);
            f32x4 r0, r1, r2, r3;
            r0 = *(const f32x4*)(pwA + quad * 8);      r1 = *(const f32x4*)(pwA + quad * 8 + 4);
            r2 = *(const f32x4*)(pwA + 32 + quad * 8); r3 = *(const f32x4*)(pwA + 32 + quad * 8 + 4);
#pragma unroll
            for (int j = 0; j < 4; ++j) { qA0[j]=(_Float16)r0[j]; qA0[4+j]=(_Float16)r1[j];
                                          qA1[j]=(_Float16)r2[j]; qA1[4+j]=(_Float16)r3[j]; }
            r0 = *(const f32x4*)(pwB + quad * 8);      r1 = *(const f32x4*)(pwB + quad * 8 + 4);
            r2 = *(const f32x4*)(pwB + 32 + quad * 8); r3 = *(const f32x4*)(pwB + 32 + quad * 8 + 4);
#pragma unroll
            for (int j = 0; j < 4; ++j) { qB0[j]=(_Float16)r0[j]; qB0[4+j]=(_Float16)r1[j];
                                          qB1[j]=(_Float16)r2[j]; qB1[4+j]=(_Float16)r3[j]; }
        }
        const float mkA = vmask[(pA << 4) + l15];
        const float mkB = vmask[(pB << 4) + l15];
        const float* xgA = xyz + rowA * 3;
        const float* xgB = xyz + rowB * 3;
        const float xgA0 = xgA[0], xgA1 = xgA[1], xgA2 = xgA[2];
        const float xgB0 = xgB[0], xgB1 = xgB[1], xgB2 = xgB[2];
        const float* xsA = xyzs + (size_t)pA * 3;
        const float* xsB = xyzs + (size_t)pB * 3;
        const float xsA0 = xsA[0], xsA1 = xsA[1], xsA2 = xsA[2];
        const float xsB0 = xsB[0], xsB1 = xsB[1], xsB2 = xsB[2];

        // prefetch next iteration's neighbor indices
        const int nbAn = nidx[(pAn << 4) + l15];
        const int nbBn = nidx[((pAn + 1) << 4) + l15];

        if (mkA == 0.0f) { qA0 = (h8)(_Float16)0.f; qA1 = (h8)(_Float16)0.f; }
        if (mkB == 0.0f) { qB0 = (h8)(_Float16)0.f; qB1 = (h8)(_Float16)0.f; }
        h8 aA2 = (h8)(_Float16)0.f, aB2 = (h8)(_Float16)0.f;
        if (quad == 0) {
            aA2[0] = (_Float16)(xgA0 * mkA - xsA0);
            aA2[1] = (_Float16)(xgA1 * mkA - xsA1);
            aA2[2] = (_Float16)(xgA2 * mkA - xsA2);
            aA2[3] = (_Float16)1.0f;               // bias channel
            aB2[0] = (_Float16)(xgB0 * mkB - xsB0);
            aB2[1] = (_Float16)(xgB1 * mkB - xsB1);
            aB2[2] = (_Float16)(xgB2 * mkB - xsB2);
            aB2[3] = (_Float16)1.0f;
        }

        // ---- layer 0 SWAPPED: D = W0'' X^T -> acc[r] = X1[16nt+4q+r][nb=l15]
        // PK pairs -> 2 adjacent u32 -> one ds_write_b64 into X'[nb][ch/2]
#pragma unroll
        for (int nt = 0; nt < 4; ++nt) {
            f32x4 aA = {0.f,0.f,0.f,0.f}, aB = {0.f,0.f,0.f,0.f};
            aA = __builtin_amdgcn_mfma_f32_16x16x32_f16(b0f[nt][0], qA0, aA, 0, 0, 0);
            aA = __builtin_amdgcn_mfma_f32_16x16x32_f16(b0f[nt][1], qA1, aA, 0, 0, 0);
            aA = __builtin_amdgcn_mfma_f32_16x16x32_f16(b0f[nt][2], aA2, aA, 0, 0, 0);
            aB = __builtin_amdgcn_mfma_f32_16x16x32_f16(b0f[nt][0], qB0, aB, 0, 0, 0);
            aB = __builtin_amdgcn_mfma_f32_16x16x32_f16(b0f[nt][1], qB1, aB, 0, 0, 0);
            aB = __builtin_amdgcn_mfma_f32_16x16x32_f16(b0f[nt][2], aB2, aB, 0, 0, 0);
            u32x2 pkA = {PK(aA[0], aA[1]), PK(aA[2], aA[3])};
            u32x2 pkB = {PK(aB[0], aB[1]), PK(aB[2], aB[3])};
            *(u32x2*)(XA + l15 * XS2_ + nt * 8 + quad * 2) = pkA;
            *(u32x2*)(XB + l15 * XS2_ + nt * 8 + quad * 2) = pkB;
        }

        // ---- layer 1 SWAPPED: X frags read as B-operand (reads precede
        // overwrites in program order; DS in-order per wave) ----
        h8 xA0 = *(const h8*)(XA + l15 * XS2_ + quad * 4);
        h8 xA1 = *(const h8*)(XA + l15 * XS2_ + 16 + quad * 4);
        h8 xB0 = *(const h8*)(XB + l15 * XS2_ + quad * 4);
        h8 xB1 = *(const h8*)(XB + l15 * XS2_ + 16 + quad * 4);
#pragma unroll 2
        for (int nt = 0; nt < 4; ++nt) {
            const _Float16* wrow = ldsW1 + (nt * 16 + l15) * WS_ + quad * 8;
            h8 wa = *(const h8*)(wrow);
            h8 wb = *(const h8*)(wrow + 32);
            const f32x4 t1 = *(const f32x4*)(t1sh + nt * 16 + quad * 4);
            f32x4 aA = t1, aB = t1;      // bias in accumulator (ch = 16nt+4q+r)
            aA = __builtin_amdgcn_mfma_f32_16x16x32_f16(wa, xA0, aA, 0, 0, 0);
            aA = __builtin_amdgcn_mfma_f32_16x16x32_f16(wb, xA1, aA, 0, 0, 0);
            aB = __builtin_amdgcn_mfma_f32_16x16x32_f16(wa, xB0, aB, 0, 0, 0);
            aB = __builtin_amdgcn_mfma_f32_16x16x32_f16(wb, xB1, aB, 0, 0, 0);
            u32x2 pkA = {PK(aA[0], aA[1]), PK(aA[2], aA[3])};
            u32x2 pkB = {PK(aB[0], aB[1]), PK(aB[2], aB[3])};
            *(u32x2*)(XA + l15 * XS2_ + nt * 8 + quad * 2) = pkA;
            *(u32x2*)(XB + l15 * XS2_ + nt * 8 + quad * 2) = pkB;
        }

        // ---- layer 2 NORMAL: X frags as A-operand + K-maxpool + stores ----
        h8 yA0 = *(const h8*)(XA + l15 * XS2_ + quad * 4);
        h8 yA1 = *(const h8*)(XA + l15 * XS2_ + 16 + quad * 4);
        h8 yB0 = *(const h8*)(XB + l15 * XS2_ + quad * 4);
        h8 yB1 = *(const h8*)(XB + l15 * XS2_ + 16 + quad * 4);
        float* obA = out + ((size_t)pA << 7);
        float* obB = out + ((size_t)pB << 7);
#pragma unroll 2
        for (int nt = 0; nt < 8; ++nt) {
            const _Float16* wrow = ldsW2 + (nt * 16 + l15) * WS_ + quad * 8;
            h8 wa = *(const h8*)(wrow);
            h8 wb = *(const h8*)(wrow + 32);
            const float t2 = t2sh[nt * 16 + l15];
            f32x4 aA = {0.f,0.f,0.f,0.f}, aB = {0.f,0.f,0.f,0.f};
            aA = __builtin_amdgcn_mfma_f32_16x16x32_f16(yA0, wa, aA, 0, 0, 0);
            aA = __builtin_amdgcn_mfma_f32_16x16x32_f16(yA1, wb, aA, 0, 0, 0);
            aB = __builtin_amdgcn_mfma_f32_16x16x32_f16(yB0, wa, aB, 0, 0, 0);
            aB = __builtin_amdgcn_mfma_f32_16x16x32_f16(yB1, wb, aB, 0, 0, 0);
            float vA = fmaxf(fmaxf(aA[0], aA[1]), fmaxf(aA[2], aA[3])) + t2;
            float vB = fmaxf(fmaxf(aB[0], aB[1]), fmaxf(aB[2], aB[3])) + t2;
            vA = fmaxf(vA, 0.f);  vB = fmaxf(vB, 0.f);    // relu(max)=max(relu)
            vA = fmaxf(vA, __shfl_xor(vA, 16, 64));
            vA = fmaxf(vA, __shfl_xor(vA, 32, 64));
            vB = fmaxf(vB, __shfl_xor(vB, 16, 64));
            vB = fmaxf(vB, __shfl_xor(vB, 32, 64));
            if (quad == 0) {
                obA[nt * 16 + l15]            = vA;
                obA[OUTHALF_ + nt * 16 + l15] = vA;
                obB[nt * 16 + l15]            = vB;
                obB[OUTHALF_ + nt * 16 + l15] = vB;
            }
        }

        nbA = nbAn; nbB = nbBn;
    }
}

extern "C" void kernel_launch(void* const* d_in, const int* in_sizes, int n_in,
                              void* d_out, int out_size, void* d_ws, size_t ws_size,
                              hipStream_t stream) {
    const float* xyz   = (const float*)d_in[0];
    const float* pts   = (const float*)d_in[1];
    const float* xyzs  = (const float*)d_in[2];
    const int*   nidx  = (const int*)d_in[3];
    const float* vmask = (const float*)d_in[4];
    const float *w0 = (const float*)d_in[5],  *b0 = (const float*)d_in[6],
                *g0 = (const float*)d_in[7],  *be0 = (const float*)d_in[8],
                *m0 = (const float*)d_in[9],  *v0 = (const float*)d_in[10];
    const float *w1 = (const float*)d_in[11], *b1 = (const float*)d_in[12],
                *g1 = (const float*)d_in[13], *be1 = (const float*)d_in[14],
                *m1 = (const float*)d_in[15], *v1 = (const float*)d_in[16];
    const float *w2 = (const float*)d_in[17], *b2 = (const float*)d_in[18],
                *g2 = (const float*)d_in[19], *be2 = (const float*)d_in[20],
                *m2 = (const float*)d_in[21], *v2 = (const float*)d_in[22];
    float* outp = (float*)d_out;

    const size_t PTS_ELEMS = 16777216ull;           // 4*65536*64
    if (ws_size >= PTS_ELEMS * sizeof(_Float16)) {
        _Float16* ptsh = (_Float16*)d_ws;
        cvt_pts_kernel<<<dim3(8192), dim3(256), 0, stream>>>(pts, ptsh);
        pnsa_main<true><<<dim3(GRID_), dim3(256), 0, stream>>>(
            xyz, (const void*)ptsh, xyzs, nidx, vmask,
            w0, b0, g0, be0, m0, v0,
            w1, b1, g1, be1, m1, v1,
            w2, b2, g2, be2, m2, v2, outp);
    } else {
        pnsa_main<false><<<dim3(GRID_), dim3(256), 0, stream>>>(
            xyz, (const void*)pts, xyzs, nidx, vmask,
            w0, b0, g0, be0, m0, v0,
            w1, b1, g1, be1, m1, v1,
            w2, b2, g2, be2, m2, v2, outp);
    }
}